// Round 24
// baseline (3071.014 us; speedup 1.0000x reference)
//
#include <hip/hip_runtime.h>

typedef unsigned short u16;
typedef unsigned int   u32;
typedef __attribute__((ext_vector_type(8))) short short8;
typedef __attribute__((ext_vector_type(4))) float f32x4;

// ---------------- constants ----------------
constexpr int Dc   = 512;
constexpr int Lc   = 6;
constexpr int Bc   = 16;
constexpr int Sc   = 2048;
constexpr int Rc   = Sc * Bc;                 // 32768 rows (b-major: r = b*S + s)
constexpr float RATIO = 0.3535533905932738f;  // 1/64^0.25
constexpr float STABc = 1e-3f;
constexpr float EPSc  = 1e-5f;

// f32 pair -> packed 2x bf16 (RNE)
__device__ __forceinline__ u32 pk2(float lo, float hi) {
    u32 a = __float_as_uint(lo), b = __float_as_uint(hi);
    a = (a + 0x7FFFu + ((a >> 16) & 1u)) >> 16;
    b = (b + 0x7FFFu + ((b >> 16) & 1u)) & 0xFFFF0000u;
    return a | b;
}
__device__ __forceinline__ u16 f2bh(float f) {
    u32 u = __float_as_uint(f);
    return (u16)((u + 0x7FFFu + ((u >> 16) & 1u)) >> 16);
}
__device__ __forceinline__ float b2f(u16 u) { return __uint_as_float(((u32)u) << 16); }

// async global->LDS, 16 bytes per lane (lane-scattered dest = base + lane*16)
__device__ __forceinline__ void glds16(const u16* g, u16* l) {
    __builtin_amdgcn_global_load_lds(
        (const __attribute__((address_space(1))) u32*)g,
        (__attribute__((address_space(3))) u32*)l, 16, 0, 0);
}

// ---------------- sentinel (ws too small diagnostic) ----------------
__global__ __launch_bounds__(256)
void sentinel_kernel(float* O, int n4) {
    int i = blockIdx.x * 256 + threadIdx.x;
    if (i < n4) {
        float4 v = make_float4(12345.f, 12345.f, 12345.f, 12345.f);
        *reinterpret_cast<float4*>(O + (size_t)i * 4) = v;
    }
}

// ---------------- zero KV/KSUM ----------------
__global__ __launch_bounds__(256)
void zero_kernel(float* p, int n4) {
    int i = blockIdx.x * 256 + threadIdx.x;
    if (i < n4) {
        float4 z = make_float4(0.f, 0.f, 0.f, 0.f);
        *reinterpret_cast<float4*>(p + (size_t)i * 4) = z;
    }
}

// ---------------- dual weight f32 -> bf16 (RNE), one dispatch for two tensors ----------------
__global__ __launch_bounds__(256)
void wconv2_kernel(const float* __restrict__ s1, u16* __restrict__ d1,
                   const float* __restrict__ s2, u16* __restrict__ d2, int n8each) {
    int i = blockIdx.x * 256 + threadIdx.x;
    const float* src; u16* dst;
    if (i < n8each) { src = s1; dst = d1; }
    else            { src = s2; dst = d2; i -= n8each; }
    if (i >= n8each) return;
    size_t base = (size_t)i * 8;
    float4 a = *reinterpret_cast<const float4*>(src + base);
    float4 b = *reinterpret_cast<const float4*>(src + base + 4);
    uint4 o;
    o.x = pk2(a.x, a.y); o.y = pk2(a.z, a.w);
    o.z = pk2(b.x, b.y); o.w = pk2(b.z, b.w);
    *reinterpret_cast<uint4*>(dst + base) = o;
}

// ---------------- XP = bf16(X + pos)  (bootstrap) ----------------
__global__ __launch_bounds__(256)
void xp_kernel(const float* __restrict__ X, const float* __restrict__ POS,
               u16* __restrict__ XP) {
    size_t i = (size_t)blockIdx.x * 256 + threadIdx.x;
    size_t base = i * 8;
    float4 x0 = *reinterpret_cast<const float4*>(X + base);
    float4 x1 = *reinterpret_cast<const float4*>(X + base + 4);
    float4 p0 = *reinterpret_cast<const float4*>(POS + base);
    float4 p1 = *reinterpret_cast<const float4*>(POS + base + 4);
    uint4 o;
    o.x = pk2(x0.x + p0.x, x0.y + p0.y);
    o.y = pk2(x0.z + p0.z, x0.w + p0.w);
    o.z = pk2(x1.x + p1.x, x1.y + p1.y);
    o.w = pk2(x1.z + p1.z, x1.w + p1.w);
    *reinterpret_cast<uint4*>(XP + base) = o;
}

// ---------------- XB = bf16(X)  (bootstrap) ----------------
__global__ __launch_bounds__(256)
void xb_kernel(const float* __restrict__ X, u16* __restrict__ XB) {
    size_t i = (size_t)blockIdx.x * 256 + threadIdx.x;
    size_t base = i * 8;
    float4 x0 = *reinterpret_cast<const float4*>(X + base);
    float4 x1 = *reinterpret_cast<const float4*>(X + base + 4);
    uint4 o;
    o.x = pk2(x0.x, x0.y); o.y = pk2(x0.z, x0.w);
    o.z = pk2(x1.x, x1.y); o.w = pk2(x1.z, x1.w);
    *reinterpret_cast<uint4*>(XB + base) = o;
}

// ---------------- Weff precompute (ORF folded; weights bf16, bias f32) ----------------
__global__ __launch_bounds__(256)
void weff_kernel(const float* __restrict__ Wqkv, const float* __restrict__ bqkv,
                 const float* __restrict__ worf,
                 u16* __restrict__ WeffQ, u16* __restrict__ WeffK,
                 float* __restrict__ beffQ, float* __restrict__ beffK) {
    __shared__ float wl[64][64];
    __shared__ float ql[64][68];
    __shared__ float kl[64][68];
    int cc = blockIdx.x, h = blockIdx.y;
    int tid = threadIdx.x;
    for (int i = tid; i < 4096; i += 256) wl[i >> 6][i & 63] = worf[i];
    for (int i = tid; i < 4096; i += 256) {
        int d = i >> 6, c = i & 63;
        ql[d][c] = Wqkv[(size_t)(h * 64 + d) * 512 + cc * 64 + c];
        kl[d][c] = Wqkv[(size_t)(512 + h * 64 + d) * 512 + cc * 64 + c];
    }
    __syncthreads();
    int m = tid >> 2, c0 = (tid & 3) * 16;
    float acc[16];
    #pragma unroll
    for (int j = 0; j < 16; ++j) acc[j] = 0.f;
    for (int d = 0; d < 64; ++d) {
        float wv = wl[m][d];
        #pragma unroll
        for (int j = 0; j < 16; ++j) acc[j] = fmaf(wv, ql[d][c0 + j], acc[j]);
    }
    for (int j = 0; j < 16; ++j)
        WeffQ[(size_t)(h * 64 + m) * 512 + cc * 64 + c0 + j] = f2bh(RATIO * acc[j]);
    #pragma unroll
    for (int j = 0; j < 16; ++j) acc[j] = 0.f;
    for (int d = 0; d < 64; ++d) {
        float wv = wl[m][d];
        #pragma unroll
        for (int j = 0; j < 16; ++j) acc[j] = fmaf(wv, kl[d][c0 + j], acc[j]);
    }
    for (int j = 0; j < 16; ++j)
        WeffK[(size_t)(h * 64 + m) * 512 + cc * 64 + c0 + j] = f2bh(RATIO * acc[j]);
    if (cc == 0 && tid < 64) {
        float bq = 0.f, bk = 0.f;
        for (int d = 0; d < 64; ++d) {
            bq = fmaf(wl[tid][d], bqkv[h * 64 + d], bq);
            bk = fmaf(wl[tid][d], bqkv[512 + h * 64 + d], bk);
        }
        beffQ[h * 64 + tid] = RATIO * bq;
        beffK[h * 64 + tid] = RATIO * bk;
    }
}

// ---------------- all-bf16 MFMA GEMM: glds + swizzle + XCD map + TRIPLE BUFFER dist-2 ----------------
// 128x128 tile, 4 waves (2x2 of 64x64), BK=32, LINEAR LDS 3x[128][32] u16 (48KB).
// Per step t: issue prefetch(t+2) into buf[(t+2)%3]; 16 MFMA on buf[t%3];
// s_waitcnt vmcnt(4) (waits ONLY tile t+1's 4 glds; t+2's stay in flight across
// the barrier - AITER pattern) + raw s_barrier, sched_barrier fences (rule #18).
// Read-side safety: buf[t%3] is next overwritten by glds issued AFTER the barrier
// at end of t, and each wave's ds_reads are register-complete pre-barrier.
// MFMA sequence identical to r23 -> bit-identical results (absmax canary 0.03125).
// MODE 0:+bias->bf16  1:relu->bf16  4:relu+STAB->bf16  2:+bias+res(f32)->f32  3:C+=acc(f32)
template <int MODE>
__global__ __launch_bounds__(256)
void gemm_bb(const u16* __restrict__ A, int lda,
             const u16* __restrict__ W, int ldw,
             const float* __restrict__ bias, const float* __restrict__ res,
             void* __restrict__ Cv, int ldc, int K) {
    constexpr bool CB16 = (MODE == 0 || MODE == 1 || MODE == 4);
    __shared__ u16 As[3][128 * 32];
    __shared__ u16 Bs[3][128 * 32];
    int tid = threadIdx.x;
    int lane = tid & 63, wv = tid >> 6;
    int wr = wv >> 1, wc = wv & 1;

    // XCD-chunked swizzle (bijective: nwg % 8 == 0 for all grids used)
    int nbx = gridDim.x;
    int nwg = nbx * gridDim.y;
    int bid = blockIdx.y * nbx + blockIdx.x;
    int nb  = (bid & 7) * (nwg >> 3) + (bid >> 3);
    int row0 = (nb / nbx) * 128;
    int col0 = (nb % nbx) * 128;

    // staging: wave wv covers rows [wv*32, wv*32+32); two 1024B glds per matrix.
    int srow  = wv * 32 + (lane >> 2);
    int skofs = (((lane & 3) ^ ((lane >> 3) & 3)) << 3);   // u16 offset, swizzled src
    const u16* Ap0 = A + (size_t)(row0 + srow) * lda + skofs;
    const u16* Ap1 = A + (size_t)(row0 + srow + 16) * lda + skofs;
    const u16* Wp0 = W + (size_t)(col0 + srow) * ldw + skofs;
    const u16* Wp1 = W + (size_t)(col0 + srow + 16) * ldw + skofs;
    int d0 = (wv * 32) * 32;
    int d1 = (wv * 32 + 16) * 32;

    f32x4 acc[4][4];
    #pragma unroll
    for (int mi = 0; mi < 4; ++mi)
        #pragma unroll
        for (int ni = 0; ni < 4; ++ni)
            acc[mi][ni] = (f32x4){0.f, 0.f, 0.f, 0.f};

    int rl = lane & 15;
    int pslot = (((lane >> 4) ^ ((rl >> 1) & 3)) << 3);    // swizzled read slot (u16)

    int nsteps = K >> 5;
    // prologue: prefetch tiles 0 and 1
    glds16(Ap0, &As[0][d0]);
    glds16(Ap1, &As[0][d1]);
    glds16(Wp0, &Bs[0][d0]);
    glds16(Wp1, &Bs[0][d1]);
    if (nsteps > 1) {
        glds16(Ap0 + 32, &As[1][d0]);
        glds16(Ap1 + 32, &As[1][d1]);
        glds16(Wp0 + 32, &Bs[1][d0]);
        glds16(Wp1 + 32, &Bs[1][d1]);
        asm volatile("s_waitcnt vmcnt(4)" ::: "memory");
    } else {
        asm volatile("s_waitcnt vmcnt(0)" ::: "memory");
    }
    __builtin_amdgcn_sched_barrier(0);
    __builtin_amdgcn_s_barrier();
    __builtin_amdgcn_sched_barrier(0);

    for (int t = 0; t < nsteps; ++t) {
        int cur = t % 3;
        if (t + 2 < nsteps) {              // prefetch tile t+2 (distance 2)
            int pf = (t + 2) % 3;
            int k2 = (t + 2) << 5;
            glds16(Ap0 + k2, &As[pf][d0]);
            glds16(Ap1 + k2, &As[pf][d1]);
            glds16(Wp0 + k2, &Bs[pf][d0]);
            glds16(Wp1 + k2, &Bs[pf][d1]);
        }
        const u16* Asr = &As[cur][0];
        const u16* Bsr = &Bs[cur][0];
        short8 af[4], bf[4];
        #pragma unroll
        for (int mi = 0; mi < 4; ++mi)
            af[mi] = *reinterpret_cast<const short8*>(&Asr[(wr * 64 + mi * 16 + rl) * 32 + pslot]);
        #pragma unroll
        for (int ni = 0; ni < 4; ++ni)
            bf[ni] = *reinterpret_cast<const short8*>(&Bsr[(wc * 64 + ni * 16 + rl) * 32 + pslot]);
        #pragma unroll
        for (int mi = 0; mi < 4; ++mi)
            #pragma unroll
            for (int ni = 0; ni < 4; ++ni)
                acc[mi][ni] = __builtin_amdgcn_mfma_f32_16x16x32_bf16(
                    af[mi], bf[ni], acc[mi][ni], 0, 0, 0);
        if (t + 1 < nsteps) {
            if (t + 2 < nsteps) asm volatile("s_waitcnt vmcnt(4)" ::: "memory");
            else                asm volatile("s_waitcnt vmcnt(0)" ::: "memory");
            __builtin_amdgcn_sched_barrier(0);
            __builtin_amdgcn_s_barrier();
            __builtin_amdgcn_sched_barrier(0);
        }
    }

    int orb = row0 + wr * 64 + (lane >> 4) * 4;
    int ocb = col0 + wc * 64 + rl;
    float bv[4];
    #pragma unroll
    for (int ni = 0; ni < 4; ++ni)
        bv[ni] = (MODE != 3) ? bias[ocb + ni * 16] : 0.f;
    #pragma unroll
    for (int mi = 0; mi < 4; ++mi) {
        #pragma unroll
        for (int j = 0; j < 4; ++j) {
            int orow = orb + mi * 16 + j;
            size_t base = (size_t)orow * ldc + ocb;
            #pragma unroll
            for (int ni = 0; ni < 4; ++ni) {
                float v = acc[mi][ni][j] + bv[ni];
                if (MODE == 1) v = fmaxf(v, 0.f);
                if (MODE == 4) v = fmaxf(v, 0.f) + STABc;
                size_t off = base + ni * 16;
                if (MODE == 2) v += res[off];
                if (MODE == 3) v += ((float*)Cv)[off];
                if (CB16) ((u16*)Cv)[off] = f2bh(v);
                else      ((float*)Cv)[off] = v;
            }
        }
    }
}

// ---------------- kv split-K: grid(128 bh, 4 sc); KP strided 1024 (in KQP), V 512 ----------------
__global__ __launch_bounds__(256)
void kv_split(const u16* __restrict__ KQP, const u16* __restrict__ V,
              float* __restrict__ KV, float* __restrict__ KSUM) {
    __shared__ u16 kpl[128 * 64];
    __shared__ u16 vl[128 * 64];
    int bh = blockIdx.x, sc = blockIdx.y;
    int b = bh >> 3, h = bh & 7;
    int tid = threadIdx.x;
    int d = tid & 63, mg = tid >> 6;        // 4 m-groups of 16
    float acc[16], ks[16];
    #pragma unroll
    for (int i = 0; i < 16; ++i) { acc[i] = 0.f; ks[i] = 0.f; }
    size_t rowbase = (size_t)b * Sc + sc * 512;
    for (int c = 0; c < 4; ++c) {
        __syncthreads();
        for (int i = tid; i < 1024; i += 256) {
            int row = i >> 3, c8 = (i & 7) * 8;
            size_t r = rowbase + c * 128 + row;
            *reinterpret_cast<uint4*>(&kpl[row * 64 + c8]) =
                *reinterpret_cast<const uint4*>(KQP + r * 1024 + h * 64 + c8);
            *reinterpret_cast<uint4*>(&vl[row * 64 + c8]) =
                *reinterpret_cast<const uint4*>(V + r * 512 + h * 64 + c8);
        }
        __syncthreads();
        for (int s = 0; s < 128; ++s) {
            float vv = b2f(vl[s * 64 + d]);
            #pragma unroll
            for (int i = 0; i < 16; ++i) {
                float kp = b2f(kpl[s * 64 + mg * 16 + i]);
                acc[i] = fmaf(kp, vv, acc[i]);
                ks[i] += kp;
            }
        }
    }
    float* kvp = KV + (size_t)bh * 4096;
    #pragma unroll
    for (int i = 0; i < 16; ++i)
        atomicAdd(&kvp[(mg * 16 + i) * 64 + d], acc[i]);
    if (d == 0) {
        #pragma unroll
        for (int i = 0; i < 16; ++i)
            atomicAdd(&KSUM[bh * 64 + mg * 16 + i], ks[i]);
    }
}

// ---------------- num/den via MFMA: QP from KQP (stride 1024, +512); den from bf16 QP ----------------
__global__ __launch_bounds__(256)
void numden_mfma(const u16* __restrict__ KQP, const float* __restrict__ KVg,
                 const float* __restrict__ KSUM, u16* __restrict__ OUT) {
    constexpr int LP = 72;
    __shared__ short Asm[128 * LP];
    __shared__ short BT[64 * LP];
    __shared__ float ksl[64];
    __shared__ float dsm[128][2];
    int h  = blockIdx.x;                   // 0..7
    int row0 = blockIdx.y * 128;
    int b  = row0 >> 11;
    int tid = threadIdx.x;
    int lane = tid & 63, w = tid >> 6;

    const float* kvp = KVg + ((size_t)(b * 8 + h)) * 4096;
    for (int i = tid; i < 4096; i += 256) {
        int m = i >> 6, d = i & 63;
        BT[d * LP + m] = (short)f2bh(kvp[i]);
    }
    if (tid < 64) ksl[tid] = KSUM[(b * 8 + h) * 64 + tid];
    {
        int rr = tid >> 1;
        int cc = (tid & 1) * 32;
        const u16* qp = KQP + (size_t)(row0 + rr) * 1024 + 512 + h * 64 + cc;
        #pragma unroll
        for (int q = 0; q < 4; ++q)
            *reinterpret_cast<uint4*>(&Asm[rr * LP + cc + q * 8]) =
                *reinterpret_cast<const uint4*>(qp + q * 8);
    }
    __syncthreads();

    // den[row] = sum_m qp_bf16[row,m] * ksum[m]  (two half-sums per row)
    {
        int rr = tid >> 1, half = tid & 1;
        const short* ap = &Asm[rr * LP + half * 32];
        float pden = 0.f;
        #pragma unroll
        for (int m = 0; m < 32; ++m)
            pden = fmaf(b2f((u16)ap[m]), ksl[half * 32 + m], pden);
        dsm[rr][half] = pden;
    }
    __syncthreads();

    int rl = lane & 15, kq = (lane >> 4) * 8;
    f32x4 acc[2][4];
    #pragma unroll
    for (int mi = 0; mi < 2; ++mi)
        #pragma unroll
        for (int ni = 0; ni < 4; ++ni) acc[mi][ni] = (f32x4){0.f, 0.f, 0.f, 0.f};
    #pragma unroll
    for (int kst = 0; kst < 2; ++kst) {
        int kg = kst * 32 + kq;
        short8 a0 = *reinterpret_cast<const short8*>(&Asm[(w * 32 + rl) * LP + kg]);
        short8 a1 = *reinterpret_cast<const short8*>(&Asm[(w * 32 + 16 + rl) * LP + kg]);
        short8 bf[4];
        #pragma unroll
        for (int ni = 0; ni < 4; ++ni)
            bf[ni] = *reinterpret_cast<const short8*>(&BT[(ni * 16 + rl) * LP + kg]);
        #pragma unroll
        for (int ni = 0; ni < 4; ++ni) {
            acc[0][ni] = __builtin_amdgcn_mfma_f32_16x16x32_bf16(a0, bf[ni], acc[0][ni], 0, 0, 0);
            acc[1][ni] = __builtin_amdgcn_mfma_f32_16x16x32_bf16(a1, bf[ni], acc[1][ni], 0, 0, 0);
        }
    }
    #pragma unroll
    for (int mi = 0; mi < 2; ++mi) {
        #pragma unroll
        for (int j = 0; j < 4; ++j) {
            int lr = w * 32 + mi * 16 + (lane >> 4) * 4 + j;
            int row = row0 + lr;
            float inv = 1.f / (dsm[lr][0] + dsm[lr][1]);
            #pragma unroll
            for (int ni = 0; ni < 4; ++ni)
                OUT[(size_t)row * Dc + h * 64 + ni * 16 + rl] =
                    f2bh(acc[mi][ni][j] * inv);
        }
    }
}

// ---------------- LayerNorm, wave per row; PERM: b-major -> [S,B,D] output ----------------
template <bool PERM>
__global__ __launch_bounds__(256)
void ln_kernel(const float* __restrict__ X, const float* __restrict__ Sg,
               const float* __restrict__ Bg, float* __restrict__ O) {
    int lane = threadIdx.x & 63, w = threadIdx.x >> 6;
    size_t r = (size_t)blockIdx.x * 4 + w;
    const float* xr = X + r * Dc;
    float v[8];
    *reinterpret_cast<float4*>(&v[0]) = *reinterpret_cast<const float4*>(xr + lane * 4);
    *reinterpret_cast<float4*>(&v[4]) = *reinterpret_cast<const float4*>(xr + 256 + lane * 4);
    float sum = 0.f;
    #pragma unroll
    for (int i = 0; i < 8; ++i) sum += v[i];
    #pragma unroll
    for (int off = 32; off >= 1; off >>= 1) sum += __shfl_xor(sum, off);
    float mu = sum * (1.f / Dc);
    float sq = 0.f;
    #pragma unroll
    for (int i = 0; i < 8; ++i) { float dd = v[i] - mu; sq += dd * dd; }
    #pragma unroll
    for (int off = 32; off >= 1; off >>= 1) sq += __shfl_xor(sq, off);
    float rstd = rsqrtf(sq * (1.f / Dc) + EPSc);
    float s[8], b[8];
    *reinterpret_cast<float4*>(&s[0]) = *reinterpret_cast<const float4*>(Sg + lane * 4);
    *reinterpret_cast<float4*>(&s[4]) = *reinterpret_cast<const float4*>(Sg + 256 + lane * 4);
    *reinterpret_cast<float4*>(&b[0]) = *reinterpret_cast<const float4*>(Bg + lane * 4);
    *reinterpret_cast<float4*>(&b[4]) = *reinterpret_cast<const float4*>(Bg + 256 + lane * 4);
    float o[8];
    #pragma unroll
    for (int i = 0; i < 8; ++i) o[i] = (v[i] - mu) * rstd * s[i] + b[i];
    size_t rd = PERM ? ((size_t)(r & (Sc - 1)) * Bc + (r >> 11)) : r;
    float* orow = O + rd * Dc;
    *reinterpret_cast<float4*>(orow + lane * 4) = *reinterpret_cast<const float4*>(&o[0]);
    *reinterpret_cast<float4*>(orow + 256 + lane * 4) = *reinterpret_cast<const float4*>(&o[4]);
}

// ---------------- ln1 fused: X=LN(X) in-place, XB=bf16(x) ----------------
__global__ __launch_bounds__(256)
void ln1f_kernel(float* __restrict__ X, const float* __restrict__ Sg,
                 const float* __restrict__ Bg, u16* __restrict__ XB) {
    int lane = threadIdx.x & 63, w = threadIdx.x >> 6;
    size_t r = (size_t)blockIdx.x * 4 + w;
    float* xr = X + r * Dc;
    float v[8];
    *reinterpret_cast<float4*>(&v[0]) = *reinterpret_cast<const float4*>(xr + lane * 4);
    *reinterpret_cast<float4*>(&v[4]) = *reinterpret_cast<const float4*>(xr + 256 + lane * 4);
    float sum = 0.f;
    #pragma unroll
    for (int i = 0; i < 8; ++i) sum += v[i];
    #pragma unroll
    for (int off = 32; off >= 1; off >>= 1) sum += __shfl_xor(sum, off);
    float mu = sum * (1.f / Dc);
    float sq = 0.f;
    #pragma unroll
    for (int i = 0; i < 8; ++i) { float dd = v[i] - mu; sq += dd * dd; }
    #pragma unroll
    for (int off = 32; off >= 1; off >>= 1) sq += __shfl_xor(sq, off);
    float rstd = rsqrtf(sq * (1.f / Dc) + EPSc);
    float s[8], b[8];
    *reinterpret_cast<float4*>(&s[0]) = *reinterpret_cast<const float4*>(Sg + lane * 4);
    *reinterpret_cast<float4*>(&s[4]) = *reinterpret_cast<const float4*>(Sg + 256 + lane * 4);
    *reinterpret_cast<float4*>(&b[0]) = *reinterpret_cast<const float4*>(Bg + lane * 4);
    *reinterpret_cast<float4*>(&b[4]) = *reinterpret_cast<const float4*>(Bg + 256 + lane * 4);
    float o[8];
    #pragma unroll
    for (int i = 0; i < 8; ++i) o[i] = (v[i] - mu) * rstd * s[i] + b[i];
    *reinterpret_cast<float4*>(xr + lane * 4)       = *reinterpret_cast<const float4*>(&o[0]);
    *reinterpret_cast<float4*>(xr + 256 + lane * 4) = *reinterpret_cast<const float4*>(&o[4]);
    uint2 xb0, xb1;
    xb0.x = pk2(o[0], o[1]); xb0.y = pk2(o[2], o[3]);
    xb1.x = pk2(o[4], o[5]); xb1.y = pk2(o[6], o[7]);
    *reinterpret_cast<uint2*>(XB + r * Dc + lane * 4)       = xb0;
    *reinterpret_cast<uint2*>(XB + r * Dc + 256 + lane * 4) = xb1;
}

// ---------------- ln2 fused: X=LN(X) in-place, XP=bf16(x+pos), XB=bf16(x) ----------------
__global__ __launch_bounds__(256)
void ln2f_kernel(float* __restrict__ X, const float* __restrict__ Sg,
                 const float* __restrict__ Bg, const float* __restrict__ POS,
                 u16* __restrict__ XP, u16* __restrict__ XB) {
    int lane = threadIdx.x & 63, w = threadIdx.x >> 6;
    size_t r = (size_t)blockIdx.x * 4 + w;
    float* xr = X + r * Dc;
    float v[8];
    *reinterpret_cast<float4*>(&v[0]) = *reinterpret_cast<const float4*>(xr + lane * 4);
    *reinterpret_cast<float4*>(&v[4]) = *reinterpret_cast<const float4*>(xr + 256 + lane * 4);
    float sum = 0.f;
    #pragma unroll
    for (int i = 0; i < 8; ++i) sum += v[i];
    #pragma unroll
    for (int off = 32; off >= 1; off >>= 1) sum += __shfl_xor(sum, off);
    float mu = sum * (1.f / Dc);
    float sq = 0.f;
    #pragma unroll
    for (int i = 0; i < 8; ++i) { float dd = v[i] - mu; sq += dd * dd; }
    #pragma unroll
    for (int off = 32; off >= 1; off >>= 1) sq += __shfl_xor(sq, off);
    float rstd = rsqrtf(sq * (1.f / Dc) + EPSc);
    float s[8], b[8];
    *reinterpret_cast<float4*>(&s[0]) = *reinterpret_cast<const float4*>(Sg + lane * 4);
    *reinterpret_cast<float4*>(&s[4]) = *reinterpret_cast<const float4*>(Sg + 256 + lane * 4);
    *reinterpret_cast<float4*>(&b[0]) = *reinterpret_cast<const float4*>(Bg + lane * 4);
    *reinterpret_cast<float4*>(&b[4]) = *reinterpret_cast<const float4*>(Bg + 256 + lane * 4);
    float p[8];
    *reinterpret_cast<float4*>(&p[0]) = *reinterpret_cast<const float4*>(POS + r * Dc + lane * 4);
    *reinterpret_cast<float4*>(&p[4]) = *reinterpret_cast<const float4*>(POS + r * Dc + 256 + lane * 4);
    float o[8];
    #pragma unroll
    for (int i = 0; i < 8; ++i) o[i] = (v[i] - mu) * rstd * s[i] + b[i];
    *reinterpret_cast<float4*>(xr + lane * 4)       = *reinterpret_cast<const float4*>(&o[0]);
    *reinterpret_cast<float4*>(xr + 256 + lane * 4) = *reinterpret_cast<const float4*>(&o[4]);
    uint2 xb0, xb1, xp0, xp1;
    xb0.x = pk2(o[0], o[1]); xb0.y = pk2(o[2], o[3]);
    xb1.x = pk2(o[4], o[5]); xb1.y = pk2(o[6], o[7]);
    xp0.x = pk2(o[0] + p[0], o[1] + p[1]); xp0.y = pk2(o[2] + p[2], o[3] + p[3]);
    xp1.x = pk2(o[4] + p[4], o[5] + p[5]); xp1.y = pk2(o[6] + p[6], o[7] + p[7]);
    *reinterpret_cast<uint2*>(XB + r * Dc + lane * 4)       = xb0;
    *reinterpret_cast<uint2*>(XB + r * Dc + 256 + lane * 4) = xb1;
    *reinterpret_cast<uint2*>(XP + r * Dc + lane * 4)       = xp0;
    *reinterpret_cast<uint2*>(XP + r * Dc + 256 + lane * 4) = xp1;
}

// ---------------- launch ----------------
extern "C" void kernel_launch(void* const* d_in, const int* in_sizes, int n_in,
                              void* d_out, int out_size, void* d_ws, size_t ws_size,
                              hipStream_t stream) {
    (void)in_sizes; (void)n_in; (void)out_size;
    const float* src   = (const float*)d_in[0];
    const float* pos   = (const float*)d_in[2];
    const float* ipw   = (const float*)d_in[3];   // [L,1536,512]
    const float* ipb   = (const float*)d_in[4];   // [L,1536]
    const float* outw  = (const float*)d_in[5];   // [L,512,512]
    const float* outb  = (const float*)d_in[6];
    const float* l1w   = (const float*)d_in[7];   // [L,2048,512]
    const float* l1b   = (const float*)d_in[8];
    const float* l2w   = (const float*)d_in[9];   // [L,512,2048]
    const float* l2b   = (const float*)d_in[10];
    const float* n1s   = (const float*)d_in[11];
    const float* n1b   = (const float*)d_in[12];
    const float* n2s   = (const float*)d_in[13];
    const float* n2b   = (const float*)d_in[14];
    const float* worf  = (const float*)d_in[15];  // [L,64,64]
    float* out = (float*)d_out;

    const size_t RD = (size_t)Rc * Dc;            // 16,777,216 elems
    // ws: X f32 | B2 f32 | KV f32 | KSUM | DEN(= WVb/WOb bf16 twins) | WeffKQ bf16 | beffKQ f32
    // NEED = 138,448,896 (proven safe; ws tail beyond this is CURSED - r10/r11/r17)
    const size_t NEED = RD * 4 + RD * 4 + (size_t)128 * 4096 * 4 + 8192 * 4
                      + (size_t)Rc * 8 * 4 + 2 * 262144 * 2 + 2 * 512 * 4;
    if (ws_size < NEED) {
        sentinel_kernel<<<(Rc * Dc / 4 + 255) / 256, 256, 0, stream>>>(out, Rc * Dc / 4);
        return;
    }
    char* p = (char*)d_ws;
    float* X    = (float*)p;  p += RD * 4;
    float* B2f  = (float*)p;  p += RD * 4;
    float* KV   = (float*)p;  p += (size_t)128 * 4096 * 4;
    float* KSUM = (float*)p;  p += 8192 * 4;
    u16*  WVb   = (u16*)p;                        // V/Wo bf16 twins live in dead DEN region
    u16*  WOb   = WVb + 262144;                   // (1 MB total, inside proven footprint)
    p += (size_t)Rc * 8 * 4;
    u16*  WeffKQ = (u16*)p;   p += 2 * 262144 * 2;   // [1024,512]: rows 0-511 K, 512-1023 Q
    float* beffKQ = (float*)p;                       // [1024]: 0-511 K, 512-1023 Q

    u16*  B2u  = (u16*)B2f;           // 2*RD u16 capacity
    u16*  XPu  = B2u;                 // [R,512] bf16(x+pos), from ln2f / bootstrap
    u16*  Vu   = B2u + RD;            // [R,512] bf16 V
    u16*  AOu  = B2u + RD;            // AO after kv (Vu dead)
    u16*  H1u  = B2u;                 // [R,2048] bf16 (XPu/AOu dead)
    u16*  OutU = (u16*)out;
    u16*  XB2u = OutU;                // lower: bf16(x) for V-GEMM (from prev ln2f)
    u16*  KQPu = OutU;                // full [R,1024]: cols 0-511 KP, 512-1023 QP
    u16*  XBu  = OutU;                // lower: bf16(ln1 x) for FFN1 (KQP dead)
    // FFN weight bf16 twins live in d_out UPPER half (dead from ln1 until layer end)
    u16*  W1bD = OutU + RD;                   // [2048,512] bf16, 2 MB
    u16*  W2bD = OutU + RD + 1048576;         // [512,2048] bf16, 2 MB

    dim3 blk(256);
    dim3 g512(4, Rc / 128);
    dim3 g1024(8, Rc / 128);
    dim3 g2048(16, Rc / 128);
    const int nz4 = (128 * 4096 + 8192) / 4;   // KV+KSUM contiguous

    for (int i = 0; i < Lc; ++i) {
        const float* w_qkv = ipw + (size_t)i * 1536 * 512;
        const float* b_qkv = ipb + (size_t)i * 1536;
        const float* w_v  = w_qkv + (size_t)1024 * 512;
        const float* b_v  = b_qkv + 1024;
        const float* w_o  = outw + (size_t)i * 512 * 512;
        const float* b_o  = outb + (size_t)i * 512;
        const float* w_1  = l1w + (size_t)i * 2048 * 512;
        const float* b_1  = l1b + (size_t)i * 2048;
        const float* w_2  = l2w + (size_t)i * 512 * 2048;
        const float* b_2  = l2b + (size_t)i * 512;
        const float* wo_i = worf + (size_t)i * 4096;

        // stacked [K;Q] effective weights: K half at base, Q half at +262144 / +512
        weff_kernel<<<dim3(8, 8), blk, 0, stream>>>(
            w_qkv, b_qkv, wo_i, WeffKQ + 262144, WeffKQ, beffKQ + 512, beffKQ);
        // V/Wo weights -> bf16 twins in dead DEN region (one dispatch)
        wconv2_kernel<<<(2 * (262144 / 8) + 255) / 256, blk, 0, stream>>>(
            w_v, WVb, w_o, WOb, 262144 / 8);

        if (i == 0) {
            hipMemcpyAsync(X, src, RD * 4, hipMemcpyDeviceToDevice, stream);
            xb_kernel<<<(int)(RD / 8 / 256), blk, 0, stream>>>(X, XB2u);
            xp_kernel<<<(int)(RD / 8 / 256), blk, 0, stream>>>(X, pos, XPu);
        }

        // V = XB2 @ WVb^T + bv -> Vu (B2 upper)
        gemm_bb<0><<<g512, blk, 0, stream>>>(
            XB2u, 512, WVb, 512, b_v, nullptr, Vu, 512, 512);
        // [KP|QP] = relu(XP @ WeffKQ^T + beffKQ) + STAB -> KQP (d_out full, ldc=1024)
        gemm_bb<4><<<g1024, blk, 0, stream>>>(
            XPu, 512, WeffKQ, 512, beffKQ, nullptr, KQPu, 1024, 512);
        // zero KV+KSUM, then kv split-K (KP strided 1024)
        zero_kernel<<<(nz4 + 255) / 256, blk, 0, stream>>>(KV, nz4);
        kv_split<<<dim3(128, 4), blk, 0, stream>>>(KQPu, Vu, KV, KSUM);
        // AO = num/den -> AOu (B2 upper; Vu dead); den computed in-kernel
        numden_mfma<<<dim3(8, Rc / 128), blk, 0, stream>>>(KQPu, KV, KSUM, AOu);
        // X = X + AO @ WOb^T + bo  (in-place f32, same-thread RMW; KQP dead)
        gemm_bb<2><<<g512, blk, 0, stream>>>(
            AOu, 512, WOb, 512, b_o, X, X, 512, 512);
        // x = LN(X) in-place + XB twin -> d_out lower (KQP dead)
        ln1f_kernel<<<Rc / 4, blk, 0, stream>>>(X, n1s + i * 512, n1b + i * 512, XBu);
        // FFN weights -> bf16 twins in d_out UPPER (one dispatch; free until layer end)
        wconv2_kernel<<<(2 * (1048576 / 8) + 255) / 256, blk, 0, stream>>>(
            w_1, W1bD, w_2, W2bD, 1048576 / 8);
        // FFN1: H1 = relu(XB @ W1b^T + b1) bf16 -> B2 full (XPu/AOu dead)
        gemm_bb<1><<<g2048, blk, 0, stream>>>(
            XBu, 512, W1bD, 512, b_1, nullptr, H1u, 2048, 512);
        // FFN2 fused: X = X + H1 @ W2b^T + b2  (K=2048, in-place f32)
        gemm_bb<2><<<g512, blk, 0, stream>>>(
            H1u, 2048, W2bD, 2048, b_2, X, X, 512, 2048);
        // ln2: last layer -> permuted d_out; else fused (X, XP, XB2 for next layer)
        if (i == Lc - 1)
            ln_kernel<true><<<Rc / 4, blk, 0, stream>>>(X, n2s + i * 512, n2b + i * 512, out);
        else
            ln2f_kernel<<<Rc / 4, blk, 0, stream>>>(X, n2s + i * 512, n2b + i * 512,
                                                    pos, XPu, XB2u);
    }
}

// Round 25
// 3011.797 us; speedup vs baseline: 1.0197x; 1.0197x over previous
//
#include <hip/hip_runtime.h>

typedef unsigned short u16;
typedef unsigned int   u32;
typedef __attribute__((ext_vector_type(8))) short short8;
typedef __attribute__((ext_vector_type(4))) float f32x4;

// ---------------- constants ----------------
constexpr int Dc   = 512;
constexpr int Lc   = 6;
constexpr int Bc   = 16;
constexpr int Sc   = 2048;
constexpr int Rc   = Sc * Bc;                 // 32768 rows (b-major: r = b*S + s)
constexpr float RATIO = 0.3535533905932738f;  // 1/64^0.25
constexpr float STABc = 1e-3f;
constexpr float EPSc  = 1e-5f;

// f32 pair -> packed 2x bf16 (RNE)
__device__ __forceinline__ u32 pk2(float lo, float hi) {
    u32 a = __float_as_uint(lo), b = __float_as_uint(hi);
    a = (a + 0x7FFFu + ((a >> 16) & 1u)) >> 16;
    b = (b + 0x7FFFu + ((b >> 16) & 1u)) & 0xFFFF0000u;
    return a | b;
}
__device__ __forceinline__ u16 f2bh(float f) {
    u32 u = __float_as_uint(f);
    return (u16)((u + 0x7FFFu + ((u >> 16) & 1u)) >> 16);
}
__device__ __forceinline__ float b2f(u16 u) { return __uint_as_float(((u32)u) << 16); }

// async global->LDS, 16 bytes per lane (lane-scattered dest = base + lane*16)
__device__ __forceinline__ void glds16(const u16* g, u16* l) {
    __builtin_amdgcn_global_load_lds(
        (const __attribute__((address_space(1))) u32*)g,
        (__attribute__((address_space(3))) u32*)l, 16, 0, 0);
}

// ---------------- sentinel (ws too small diagnostic) ----------------
__global__ __launch_bounds__(256)
void sentinel_kernel(float* O, int n4) {
    int i = blockIdx.x * 256 + threadIdx.x;
    if (i < n4) {
        float4 v = make_float4(12345.f, 12345.f, 12345.f, 12345.f);
        *reinterpret_cast<float4*>(O + (size_t)i * 4) = v;
    }
}

// ---------------- zero KV/KSUM ----------------
__global__ __launch_bounds__(256)
void zero_kernel(float* p, int n4) {
    int i = blockIdx.x * 256 + threadIdx.x;
    if (i < n4) {
        float4 z = make_float4(0.f, 0.f, 0.f, 0.f);
        *reinterpret_cast<float4*>(p + (size_t)i * 4) = z;
    }
}

// ---------------- dual weight f32 -> bf16 (RNE), one dispatch for two tensors ----------------
__global__ __launch_bounds__(256)
void wconv2_kernel(const float* __restrict__ s1, u16* __restrict__ d1,
                   const float* __restrict__ s2, u16* __restrict__ d2, int n8each) {
    int i = blockIdx.x * 256 + threadIdx.x;
    const float* src; u16* dst;
    if (i < n8each) { src = s1; dst = d1; }
    else            { src = s2; dst = d2; i -= n8each; }
    if (i >= n8each) return;
    size_t base = (size_t)i * 8;
    float4 a = *reinterpret_cast<const float4*>(src + base);
    float4 b = *reinterpret_cast<const float4*>(src + base + 4);
    uint4 o;
    o.x = pk2(a.x, a.y); o.y = pk2(a.z, a.w);
    o.z = pk2(b.x, b.y); o.w = pk2(b.z, b.w);
    *reinterpret_cast<uint4*>(dst + base) = o;
}

// ---------------- XP = bf16(X + pos)  (bootstrap) ----------------
__global__ __launch_bounds__(256)
void xp_kernel(const float* __restrict__ X, const float* __restrict__ POS,
               u16* __restrict__ XP) {
    size_t i = (size_t)blockIdx.x * 256 + threadIdx.x;
    size_t base = i * 8;
    float4 x0 = *reinterpret_cast<const float4*>(X + base);
    float4 x1 = *reinterpret_cast<const float4*>(X + base + 4);
    float4 p0 = *reinterpret_cast<const float4*>(POS + base);
    float4 p1 = *reinterpret_cast<const float4*>(POS + base + 4);
    uint4 o;
    o.x = pk2(x0.x + p0.x, x0.y + p0.y);
    o.y = pk2(x0.z + p0.z, x0.w + p0.w);
    o.z = pk2(x1.x + p1.x, x1.y + p1.y);
    o.w = pk2(x1.z + p1.z, x1.w + p1.w);
    *reinterpret_cast<uint4*>(XP + base) = o;
}

// ---------------- XB = bf16(X)  (bootstrap) ----------------
__global__ __launch_bounds__(256)
void xb_kernel(const float* __restrict__ X, u16* __restrict__ XB) {
    size_t i = (size_t)blockIdx.x * 256 + threadIdx.x;
    size_t base = i * 8;
    float4 x0 = *reinterpret_cast<const float4*>(X + base);
    float4 x1 = *reinterpret_cast<const float4*>(X + base + 4);
    uint4 o;
    o.x = pk2(x0.x, x0.y); o.y = pk2(x0.z, x0.w);
    o.z = pk2(x1.x, x1.y); o.w = pk2(x1.z, x1.w);
    *reinterpret_cast<uint4*>(XB + base) = o;
}

// ---------------- Weff precompute (ORF folded; weights bf16, bias f32) ----------------
__global__ __launch_bounds__(256)
void weff_kernel(const float* __restrict__ Wqkv, const float* __restrict__ bqkv,
                 const float* __restrict__ worf,
                 u16* __restrict__ WeffQ, u16* __restrict__ WeffK,
                 float* __restrict__ beffQ, float* __restrict__ beffK) {
    __shared__ float wl[64][64];
    __shared__ float ql[64][68];
    __shared__ float kl[64][68];
    int cc = blockIdx.x, h = blockIdx.y;
    int tid = threadIdx.x;
    for (int i = tid; i < 4096; i += 256) wl[i >> 6][i & 63] = worf[i];
    for (int i = tid; i < 4096; i += 256) {
        int d = i >> 6, c = i & 63;
        ql[d][c] = Wqkv[(size_t)(h * 64 + d) * 512 + cc * 64 + c];
        kl[d][c] = Wqkv[(size_t)(512 + h * 64 + d) * 512 + cc * 64 + c];
    }
    __syncthreads();
    int m = tid >> 2, c0 = (tid & 3) * 16;
    float acc[16];
    #pragma unroll
    for (int j = 0; j < 16; ++j) acc[j] = 0.f;
    for (int d = 0; d < 64; ++d) {
        float wv = wl[m][d];
        #pragma unroll
        for (int j = 0; j < 16; ++j) acc[j] = fmaf(wv, ql[d][c0 + j], acc[j]);
    }
    for (int j = 0; j < 16; ++j)
        WeffQ[(size_t)(h * 64 + m) * 512 + cc * 64 + c0 + j] = f2bh(RATIO * acc[j]);
    #pragma unroll
    for (int j = 0; j < 16; ++j) acc[j] = 0.f;
    for (int d = 0; d < 64; ++d) {
        float wv = wl[m][d];
        #pragma unroll
        for (int j = 0; j < 16; ++j) acc[j] = fmaf(wv, kl[d][c0 + j], acc[j]);
    }
    for (int j = 0; j < 16; ++j)
        WeffK[(size_t)(h * 64 + m) * 512 + cc * 64 + c0 + j] = f2bh(RATIO * acc[j]);
    if (cc == 0 && tid < 64) {
        float bq = 0.f, bk = 0.f;
        for (int d = 0; d < 64; ++d) {
            bq = fmaf(wl[tid][d], bqkv[h * 64 + d], bq);
            bk = fmaf(wl[tid][d], bqkv[512 + h * 64 + d], bk);
        }
        beffQ[h * 64 + tid] = RATIO * bq;
        beffK[h * 64 + tid] = RATIO * bk;
    }
}

// ---------------- all-bf16 MFMA GEMM: glds + XOR swizzle + XCD map + DOUBLE BUFFER ----------------
// 128x128 tile, 4 waves (2x2 of 64x64), BK=32, LINEAR LDS 2x[128][32] u16.
// Per step: prefetch tile t+1 into buf^1, compute tile t from buf, ONE barrier.
// MODE 0:+bias->bf16  1:relu->bf16  4:relu+STAB->bf16  2:+bias+res(f32)->f32  3:C+=acc(f32)
template <int MODE>
__global__ __launch_bounds__(256)
void gemm_bb(const u16* __restrict__ A, int lda,
             const u16* __restrict__ W, int ldw,
             const float* __restrict__ bias, const float* __restrict__ res,
             void* __restrict__ Cv, int ldc, int K) {
    constexpr bool CB16 = (MODE == 0 || MODE == 1 || MODE == 4);
    __shared__ u16 As[2][128 * 32];
    __shared__ u16 Bs[2][128 * 32];
    int tid = threadIdx.x;
    int lane = tid & 63, wv = tid >> 6;
    int wr = wv >> 1, wc = wv & 1;

    // XCD-chunked swizzle (bijective: nwg % 8 == 0 for all grids used)
    int nbx = gridDim.x;
    int nwg = nbx * gridDim.y;
    int bid = blockIdx.y * nbx + blockIdx.x;
    int nb  = (bid & 7) * (nwg >> 3) + (bid >> 3);
    int row0 = (nb / nbx) * 128;
    int col0 = (nb % nbx) * 128;

    // staging: wave wv covers rows [wv*32, wv*32+32); two 1024B glds per matrix.
    int srow  = wv * 32 + (lane >> 2);
    int skofs = (((lane & 3) ^ ((lane >> 3) & 3)) << 3);   // u16 offset, swizzled src
    const u16* Ap0 = A + (size_t)(row0 + srow) * lda + skofs;
    const u16* Ap1 = A + (size_t)(row0 + srow + 16) * lda + skofs;
    const u16* Wp0 = W + (size_t)(col0 + srow) * ldw + skofs;
    const u16* Wp1 = W + (size_t)(col0 + srow + 16) * ldw + skofs;
    int d0 = (wv * 32) * 32;
    int d1 = (wv * 32 + 16) * 32;

    f32x4 acc[4][4];
    #pragma unroll
    for (int mi = 0; mi < 4; ++mi)
        #pragma unroll
        for (int ni = 0; ni < 4; ++ni)
            acc[mi][ni] = (f32x4){0.f, 0.f, 0.f, 0.f};

    int rl = lane & 15;
    int pslot = (((lane >> 4) ^ ((rl >> 1) & 3)) << 3);    // swizzled read slot (u16)

    // prologue: stage tile 0 into buf 0
    glds16(Ap0, &As[0][d0]);
    glds16(Ap1, &As[0][d1]);
    glds16(Wp0, &Bs[0][d0]);
    glds16(Wp1, &Bs[0][d1]);
    __syncthreads();                       // drain -> tile 0 resident

    int nsteps = K >> 5;
    for (int t = 0; t < nsteps; ++t) {
        int cur = t & 1;
        if (t + 1 < nsteps) {              // prefetch next tile into other buffer
            int k1 = (t + 1) << 5;
            glds16(Ap0 + k1, &As[cur ^ 1][d0]);
            glds16(Ap1 + k1, &As[cur ^ 1][d1]);
            glds16(Wp0 + k1, &Bs[cur ^ 1][d0]);
            glds16(Wp1 + k1, &Bs[cur ^ 1][d1]);
        }
        const u16* Asr = &As[cur][0];
        const u16* Bsr = &Bs[cur][0];
        short8 af[4], bf[4];
        #pragma unroll
        for (int mi = 0; mi < 4; ++mi)
            af[mi] = *reinterpret_cast<const short8*>(&Asr[(wr * 64 + mi * 16 + rl) * 32 + pslot]);
        #pragma unroll
        for (int ni = 0; ni < 4; ++ni)
            bf[ni] = *reinterpret_cast<const short8*>(&Bsr[(wc * 64 + ni * 16 + rl) * 32 + pslot]);
        #pragma unroll
        for (int mi = 0; mi < 4; ++mi)
            #pragma unroll
            for (int ni = 0; ni < 4; ++ni)
                acc[mi][ni] = __builtin_amdgcn_mfma_f32_16x16x32_bf16(
                    af[mi], bf[ni], acc[mi][ni], 0, 0, 0);
        __syncthreads();                   // drains prefetch (overlapped) + read fence
    }

    int orb = row0 + wr * 64 + (lane >> 4) * 4;
    int ocb = col0 + wc * 64 + rl;
    float bv[4];
    #pragma unroll
    for (int ni = 0; ni < 4; ++ni)
        bv[ni] = (MODE != 3) ? bias[ocb + ni * 16] : 0.f;
    #pragma unroll
    for (int mi = 0; mi < 4; ++mi) {
        #pragma unroll
        for (int j = 0; j < 4; ++j) {
            int orow = orb + mi * 16 + j;
            size_t base = (size_t)orow * ldc + ocb;
            #pragma unroll
            for (int ni = 0; ni < 4; ++ni) {
                float v = acc[mi][ni][j] + bv[ni];
                if (MODE == 1) v = fmaxf(v, 0.f);
                if (MODE == 4) v = fmaxf(v, 0.f) + STABc;
                size_t off = base + ni * 16;
                if (MODE == 2) v += res[off];
                if (MODE == 3) v += ((float*)Cv)[off];
                if (CB16) ((u16*)Cv)[off] = f2bh(v);
                else      ((float*)Cv)[off] = v;
            }
        }
    }
}

// ---------------- kv split-K: grid(128 bh, 4 sc); KP strided 1024 (in KQP), V 512 ----------------
__global__ __launch_bounds__(256)
void kv_split(const u16* __restrict__ KQP, const u16* __restrict__ V,
              float* __restrict__ KV, float* __restrict__ KSUM) {
    __shared__ u16 kpl[128 * 64];
    __shared__ u16 vl[128 * 64];
    int bh = blockIdx.x, sc = blockIdx.y;
    int b = bh >> 3, h = bh & 7;
    int tid = threadIdx.x;
    int d = tid & 63, mg = tid >> 6;        // 4 m-groups of 16
    float acc[16], ks[16];
    #pragma unroll
    for (int i = 0; i < 16; ++i) { acc[i] = 0.f; ks[i] = 0.f; }
    size_t rowbase = (size_t)b * Sc + sc * 512;
    for (int c = 0; c < 4; ++c) {
        __syncthreads();
        for (int i = tid; i < 1024; i += 256) {
            int row = i >> 3, c8 = (i & 7) * 8;
            size_t r = rowbase + c * 128 + row;
            *reinterpret_cast<uint4*>(&kpl[row * 64 + c8]) =
                *reinterpret_cast<const uint4*>(KQP + r * 1024 + h * 64 + c8);
            *reinterpret_cast<uint4*>(&vl[row * 64 + c8]) =
                *reinterpret_cast<const uint4*>(V + r * 512 + h * 64 + c8);
        }
        __syncthreads();
        for (int s = 0; s < 128; ++s) {
            float vv = b2f(vl[s * 64 + d]);
            #pragma unroll
            for (int i = 0; i < 16; ++i) {
                float kp = b2f(kpl[s * 64 + mg * 16 + i]);
                acc[i] = fmaf(kp, vv, acc[i]);
                ks[i] += kp;
            }
        }
    }
    float* kvp = KV + (size_t)bh * 4096;
    #pragma unroll
    for (int i = 0; i < 16; ++i)
        atomicAdd(&kvp[(mg * 16 + i) * 64 + d], acc[i]);
    if (d == 0) {
        #pragma unroll
        for (int i = 0; i < 16; ++i)
            atomicAdd(&KSUM[bh * 64 + mg * 16 + i], ks[i]);
    }
}

// ---------------- num/den via MFMA: QP from KQP (stride 1024, +512); den from bf16 QP ----------------
__global__ __launch_bounds__(256)
void numden_mfma(const u16* __restrict__ KQP, const float* __restrict__ KVg,
                 const float* __restrict__ KSUM, u16* __restrict__ OUT) {
    constexpr int LP = 72;
    __shared__ short Asm[128 * LP];
    __shared__ short BT[64 * LP];
    __shared__ float ksl[64];
    __shared__ float dsm[128][2];
    int h  = blockIdx.x;                   // 0..7
    int row0 = blockIdx.y * 128;
    int b  = row0 >> 11;
    int tid = threadIdx.x;
    int lane = tid & 63, w = tid >> 6;

    const float* kvp = KVg + ((size_t)(b * 8 + h)) * 4096;
    for (int i = tid; i < 4096; i += 256) {
        int m = i >> 6, d = i & 63;
        BT[d * LP + m] = (short)f2bh(kvp[i]);
    }
    if (tid < 64) ksl[tid] = KSUM[(b * 8 + h) * 64 + tid];
    {
        int rr = tid >> 1;
        int cc = (tid & 1) * 32;
        const u16* qp = KQP + (size_t)(row0 + rr) * 1024 + 512 + h * 64 + cc;
        #pragma unroll
        for (int q = 0; q < 4; ++q)
            *reinterpret_cast<uint4*>(&Asm[rr * LP + cc + q * 8]) =
                *reinterpret_cast<const uint4*>(qp + q * 8);
    }
    __syncthreads();

    // den[row] = sum_m qp_bf16[row,m] * ksum[m]  (two half-sums per row)
    {
        int rr = tid >> 1, half = tid & 1;
        const short* ap = &Asm[rr * LP + half * 32];
        float pden = 0.f;
        #pragma unroll
        for (int m = 0; m < 32; ++m)
            pden = fmaf(b2f((u16)ap[m]), ksl[half * 32 + m], pden);
        dsm[rr][half] = pden;
    }
    __syncthreads();

    int rl = lane & 15, kq = (lane >> 4) * 8;
    f32x4 acc[2][4];
    #pragma unroll
    for (int mi = 0; mi < 2; ++mi)
        #pragma unroll
        for (int ni = 0; ni < 4; ++ni) acc[mi][ni] = (f32x4){0.f, 0.f, 0.f, 0.f};
    #pragma unroll
    for (int kst = 0; kst < 2; ++kst) {
        int kg = kst * 32 + kq;
        short8 a0 = *reinterpret_cast<const short8*>(&Asm[(w * 32 + rl) * LP + kg]);
        short8 a1 = *reinterpret_cast<const short8*>(&Asm[(w * 32 + 16 + rl) * LP + kg]);
        short8 bf[4];
        #pragma unroll
        for (int ni = 0; ni < 4; ++ni)
            bf[ni] = *reinterpret_cast<const short8*>(&BT[(ni * 16 + rl) * LP + kg]);
        #pragma unroll
        for (int ni = 0; ni < 4; ++ni) {
            acc[0][ni] = __builtin_amdgcn_mfma_f32_16x16x32_bf16(a0, bf[ni], acc[0][ni], 0, 0, 0);
            acc[1][ni] = __builtin_amdgcn_mfma_f32_16x16x32_bf16(a1, bf[ni], acc[1][ni], 0, 0, 0);
        }
    }
    #pragma unroll
    for (int mi = 0; mi < 2; ++mi) {
        #pragma unroll
        for (int j = 0; j < 4; ++j) {
            int lr = w * 32 + mi * 16 + (lane >> 4) * 4 + j;
            int row = row0 + lr;
            float inv = 1.f / (dsm[lr][0] + dsm[lr][1]);
            #pragma unroll
            for (int ni = 0; ni < 4; ++ni)
                OUT[(size_t)row * Dc + h * 64 + ni * 16 + rl] =
                    f2bh(acc[mi][ni][j] * inv);
        }
    }
}

// ---------------- LayerNorm, wave per row; PERM: b-major -> [S,B,D] output ----------------
template <bool PERM>
__global__ __launch_bounds__(256)
void ln_kernel(const float* __restrict__ X, const float* __restrict__ Sg,
               const float* __restrict__ Bg, float* __restrict__ O) {
    int lane = threadIdx.x & 63, w = threadIdx.x >> 6;
    size_t r = (size_t)blockIdx.x * 4 + w;
    const float* xr = X + r * Dc;
    float v[8];
    *reinterpret_cast<float4*>(&v[0]) = *reinterpret_cast<const float4*>(xr + lane * 4);
    *reinterpret_cast<float4*>(&v[4]) = *reinterpret_cast<const float4*>(xr + 256 + lane * 4);
    float sum = 0.f;
    #pragma unroll
    for (int i = 0; i < 8; ++i) sum += v[i];
    #pragma unroll
    for (int off = 32; off >= 1; off >>= 1) sum += __shfl_xor(sum, off);
    float mu = sum * (1.f / Dc);
    float sq = 0.f;
    #pragma unroll
    for (int i = 0; i < 8; ++i) { float dd = v[i] - mu; sq += dd * dd; }
    #pragma unroll
    for (int off = 32; off >= 1; off >>= 1) sq += __shfl_xor(sq, off);
    float rstd = rsqrtf(sq * (1.f / Dc) + EPSc);
    float s[8], b[8];
    *reinterpret_cast<float4*>(&s[0]) = *reinterpret_cast<const float4*>(Sg + lane * 4);
    *reinterpret_cast<float4*>(&s[4]) = *reinterpret_cast<const float4*>(Sg + 256 + lane * 4);
    *reinterpret_cast<float4*>(&b[0]) = *reinterpret_cast<const float4*>(Bg + lane * 4);
    *reinterpret_cast<float4*>(&b[4]) = *reinterpret_cast<const float4*>(Bg + 256 + lane * 4);
    float o[8];
    #pragma unroll
    for (int i = 0; i < 8; ++i) o[i] = (v[i] - mu) * rstd * s[i] + b[i];
    size_t rd = PERM ? ((size_t)(r & (Sc - 1)) * Bc + (r >> 11)) : r;
    float* orow = O + rd * Dc;
    *reinterpret_cast<float4*>(orow + lane * 4) = *reinterpret_cast<const float4*>(&o[0]);
    *reinterpret_cast<float4*>(orow + 256 + lane * 4) = *reinterpret_cast<const float4*>(&o[4]);
}

// ---------------- ln1 fused: X=LN(X) in-place, XB=bf16(x) ----------------
__global__ __launch_bounds__(256)
void ln1f_kernel(float* __restrict__ X, const float* __restrict__ Sg,
                 const float* __restrict__ Bg, u16* __restrict__ XB) {
    int lane = threadIdx.x & 63, w = threadIdx.x >> 6;
    size_t r = (size_t)blockIdx.x * 4 + w;
    float* xr = X + r * Dc;
    float v[8];
    *reinterpret_cast<float4*>(&v[0]) = *reinterpret_cast<const float4*>(xr + lane * 4);
    *reinterpret_cast<float4*>(&v[4]) = *reinterpret_cast<const float4*>(xr + 256 + lane * 4);
    float sum = 0.f;
    #pragma unroll
    for (int i = 0; i < 8; ++i) sum += v[i];
    #pragma unroll
    for (int off = 32; off >= 1; off >>= 1) sum += __shfl_xor(sum, off);
    float mu = sum * (1.f / Dc);
    float sq = 0.f;
    #pragma unroll
    for (int i = 0; i < 8; ++i) { float dd = v[i] - mu; sq += dd * dd; }
    #pragma unroll
    for (int off = 32; off >= 1; off >>= 1) sq += __shfl_xor(sq, off);
    float rstd = rsqrtf(sq * (1.f / Dc) + EPSc);
    float s[8], b[8];
    *reinterpret_cast<float4*>(&s[0]) = *reinterpret_cast<const float4*>(Sg + lane * 4);
    *reinterpret_cast<float4*>(&s[4]) = *reinterpret_cast<const float4*>(Sg + 256 + lane * 4);
    *reinterpret_cast<float4*>(&b[0]) = *reinterpret_cast<const float4*>(Bg + lane * 4);
    *reinterpret_cast<float4*>(&b[4]) = *reinterpret_cast<const float4*>(Bg + 256 + lane * 4);
    float o[8];
    #pragma unroll
    for (int i = 0; i < 8; ++i) o[i] = (v[i] - mu) * rstd * s[i] + b[i];
    *reinterpret_cast<float4*>(xr + lane * 4)       = *reinterpret_cast<const float4*>(&o[0]);
    *reinterpret_cast<float4*>(xr + 256 + lane * 4) = *reinterpret_cast<const float4*>(&o[4]);
    uint2 xb0, xb1;
    xb0.x = pk2(o[0], o[1]); xb0.y = pk2(o[2], o[3]);
    xb1.x = pk2(o[4], o[5]); xb1.y = pk2(o[6], o[7]);
    *reinterpret_cast<uint2*>(XB + r * Dc + lane * 4)       = xb0;
    *reinterpret_cast<uint2*>(XB + r * Dc + 256 + lane * 4) = xb1;
}

// ---------------- ln2 fused: X=LN(X) in-place, XP=bf16(x+pos), XB=bf16(x) ----------------
__global__ __launch_bounds__(256)
void ln2f_kernel(float* __restrict__ X, const float* __restrict__ Sg,
                 const float* __restrict__ Bg, const float* __restrict__ POS,
                 u16* __restrict__ XP, u16* __restrict__ XB) {
    int lane = threadIdx.x & 63, w = threadIdx.x >> 6;
    size_t r = (size_t)blockIdx.x * 4 + w;
    float* xr = X + r * Dc;
    float v[8];
    *reinterpret_cast<float4*>(&v[0]) = *reinterpret_cast<const float4*>(xr + lane * 4);
    *reinterpret_cast<float4*>(&v[4]) = *reinterpret_cast<const float4*>(xr + 256 + lane * 4);
    float sum = 0.f;
    #pragma unroll
    for (int i = 0; i < 8; ++i) sum += v[i];
    #pragma unroll
    for (int off = 32; off >= 1; off >>= 1) sum += __shfl_xor(sum, off);
    float mu = sum * (1.f / Dc);
    float sq = 0.f;
    #pragma unroll
    for (int i = 0; i < 8; ++i) { float dd = v[i] - mu; sq += dd * dd; }
    #pragma unroll
    for (int off = 32; off >= 1; off >>= 1) sq += __shfl_xor(sq, off);
    float rstd = rsqrtf(sq * (1.f / Dc) + EPSc);
    float s[8], b[8];
    *reinterpret_cast<float4*>(&s[0]) = *reinterpret_cast<const float4*>(Sg + lane * 4);
    *reinterpret_cast<float4*>(&s[4]) = *reinterpret_cast<const float4*>(Sg + 256 + lane * 4);
    *reinterpret_cast<float4*>(&b[0]) = *reinterpret_cast<const float4*>(Bg + lane * 4);
    *reinterpret_cast<float4*>(&b[4]) = *reinterpret_cast<const float4*>(Bg + 256 + lane * 4);
    float p[8];
    *reinterpret_cast<float4*>(&p[0]) = *reinterpret_cast<const float4*>(POS + r * Dc + lane * 4);
    *reinterpret_cast<float4*>(&p[4]) = *reinterpret_cast<const float4*>(POS + r * Dc + 256 + lane * 4);
    float o[8];
    #pragma unroll
    for (int i = 0; i < 8; ++i) o[i] = (v[i] - mu) * rstd * s[i] + b[i];
    *reinterpret_cast<float4*>(xr + lane * 4)       = *reinterpret_cast<const float4*>(&o[0]);
    *reinterpret_cast<float4*>(xr + 256 + lane * 4) = *reinterpret_cast<const float4*>(&o[4]);
    uint2 xb0, xb1, xp0, xp1;
    xb0.x = pk2(o[0], o[1]); xb0.y = pk2(o[2], o[3]);
    xb1.x = pk2(o[4], o[5]); xb1.y = pk2(o[6], o[7]);
    xp0.x = pk2(o[0] + p[0], o[1] + p[1]); xp0.y = pk2(o[2] + p[2], o[3] + p[3]);
    xp1.x = pk2(o[4] + p[4], o[5] + p[5]); xp1.y = pk2(o[6] + p[6], o[7] + p[7]);
    *reinterpret_cast<uint2*>(XB + r * Dc + lane * 4)       = xb0;
    *reinterpret_cast<uint2*>(XB + r * Dc + 256 + lane * 4) = xb1;
    *reinterpret_cast<uint2*>(XP + r * Dc + lane * 4)       = xp0;
    *reinterpret_cast<uint2*>(XP + r * Dc + 256 + lane * 4) = xp1;
}

// ---------------- launch ----------------
extern "C" void kernel_launch(void* const* d_in, const int* in_sizes, int n_in,
                              void* d_out, int out_size, void* d_ws, size_t ws_size,
                              hipStream_t stream) {
    (void)in_sizes; (void)n_in; (void)out_size;
    const float* src   = (const float*)d_in[0];
    const float* pos   = (const float*)d_in[2];
    const float* ipw   = (const float*)d_in[3];   // [L,1536,512]
    const float* ipb   = (const float*)d_in[4];   // [L,1536]
    const float* outw  = (const float*)d_in[5];   // [L,512,512]
    const float* outb  = (const float*)d_in[6];
    const float* l1w   = (const float*)d_in[7];   // [L,2048,512]
    const float* l1b   = (const float*)d_in[8];
    const float* l2w   = (const float*)d_in[9];   // [L,512,2048]
    const float* l2b   = (const float*)d_in[10];
    const float* n1s   = (const float*)d_in[11];
    const float* n1b   = (const float*)d_in[12];
    const float* n2s   = (const float*)d_in[13];
    const float* n2b   = (const float*)d_in[14];
    const float* worf  = (const float*)d_in[15];  // [L,64,64]
    float* out = (float*)d_out;

    const size_t RD = (size_t)Rc * Dc;            // 16,777,216 elems
    // ws: X f32 | B2 f32 | KV f32 | KSUM | DEN(= WVb/WOb bf16 twins) | WeffKQ bf16 | beffKQ f32
    // NEED = 138,448,896 (proven safe; ws tail beyond this is CURSED - r10/r11/r17)
    const size_t NEED = RD * 4 + RD * 4 + (size_t)128 * 4096 * 4 + 8192 * 4
                      + (size_t)Rc * 8 * 4 + 2 * 262144 * 2 + 2 * 512 * 4;
    if (ws_size < NEED) {
        sentinel_kernel<<<(Rc * Dc / 4 + 255) / 256, 256, 0, stream>>>(out, Rc * Dc / 4);
        return;
    }
    char* p = (char*)d_ws;
    float* X    = (float*)p;  p += RD * 4;
    float* B2f  = (float*)p;  p += RD * 4;
    float* KV   = (float*)p;  p += (size_t)128 * 4096 * 4;
    float* KSUM = (float*)p;  p += 8192 * 4;
    u16*  WVb   = (u16*)p;                        // V/Wo bf16 twins live in dead DEN region
    u16*  WOb   = WVb + 262144;                   // (1 MB total, inside proven footprint)
    p += (size_t)Rc * 8 * 4;
    u16*  WeffKQ = (u16*)p;   p += 2 * 262144 * 2;   // [1024,512]: rows 0-511 K, 512-1023 Q
    float* beffKQ = (float*)p;                       // [1024]: 0-511 K, 512-1023 Q

    u16*  B2u  = (u16*)B2f;           // 2*RD u16 capacity
    u16*  XPu  = B2u;                 // [R,512] bf16(x+pos), from ln2f / bootstrap
    u16*  Vu   = B2u + RD;            // [R,512] bf16 V
    u16*  AOu  = B2u + RD;            // AO after kv (Vu dead)
    u16*  H1u  = B2u;                 // [R,2048] bf16 (XPu/AOu dead)
    u16*  OutU = (u16*)out;
    u16*  XB2u = OutU;                // lower: bf16(x) for V-GEMM (from prev ln2f)
    u16*  KQPu = OutU;                // full [R,1024]: cols 0-511 KP, 512-1023 QP
    u16*  XBu  = OutU;                // lower: bf16(ln1 x) for FFN1 (KQP dead)
    // FFN weight bf16 twins live in d_out UPPER half (dead from ln1 until layer end)
    u16*  W1bD = OutU + RD;                   // [2048,512] bf16, 2 MB
    u16*  W2bD = OutU + RD + 1048576;         // [512,2048] bf16, 2 MB

    dim3 blk(256);
    dim3 g512(4, Rc / 128);
    dim3 g1024(8, Rc / 128);
    dim3 g2048(16, Rc / 128);
    const int nz4 = (128 * 4096 + 8192) / 4;   // KV+KSUM contiguous

    for (int i = 0; i < Lc; ++i) {
        const float* w_qkv = ipw + (size_t)i * 1536 * 512;
        const float* b_qkv = ipb + (size_t)i * 1536;
        const float* w_v  = w_qkv + (size_t)1024 * 512;
        const float* b_v  = b_qkv + 1024;
        const float* w_o  = outw + (size_t)i * 512 * 512;
        const float* b_o  = outb + (size_t)i * 512;
        const float* w_1  = l1w + (size_t)i * 2048 * 512;
        const float* b_1  = l1b + (size_t)i * 2048;
        const float* w_2  = l2w + (size_t)i * 512 * 2048;
        const float* b_2  = l2b + (size_t)i * 512;
        const float* wo_i = worf + (size_t)i * 4096;

        // stacked [K;Q] effective weights: K half at base, Q half at +262144 / +512
        weff_kernel<<<dim3(8, 8), blk, 0, stream>>>(
            w_qkv, b_qkv, wo_i, WeffKQ + 262144, WeffKQ, beffKQ + 512, beffKQ);
        // V/Wo weights -> bf16 twins in dead DEN region (one dispatch)
        wconv2_kernel<<<(2 * (262144 / 8) + 255) / 256, blk, 0, stream>>>(
            w_v, WVb, w_o, WOb, 262144 / 8);

        if (i == 0) {
            hipMemcpyAsync(X, src, RD * 4, hipMemcpyDeviceToDevice, stream);
            xb_kernel<<<(int)(RD / 8 / 256), blk, 0, stream>>>(X, XB2u);
            xp_kernel<<<(int)(RD / 8 / 256), blk, 0, stream>>>(X, pos, XPu);
        }

        // V = XB2 @ WVb^T + bv -> Vu (B2 upper)
        gemm_bb<0><<<g512, blk, 0, stream>>>(
            XB2u, 512, WVb, 512, b_v, nullptr, Vu, 512, 512);
        // [KP|QP] = relu(XP @ WeffKQ^T + beffKQ) + STAB -> KQP (d_out full, ldc=1024)
        gemm_bb<4><<<g1024, blk, 0, stream>>>(
            XPu, 512, WeffKQ, 512, beffKQ, nullptr, KQPu, 1024, 512);
        // zero KV+KSUM, then kv split-K (KP strided 1024)
        zero_kernel<<<(nz4 + 255) / 256, blk, 0, stream>>>(KV, nz4);
        kv_split<<<dim3(128, 4), blk, 0, stream>>>(KQPu, Vu, KV, KSUM);
        // AO = num/den -> AOu (B2 upper; Vu dead); den computed in-kernel
        numden_mfma<<<dim3(8, Rc / 128), blk, 0, stream>>>(KQPu, KV, KSUM, AOu);
        // X = X + AO @ WOb^T + bo  (in-place f32, same-thread RMW; KQP dead)
        gemm_bb<2><<<g512, blk, 0, stream>>>(
            AOu, 512, WOb, 512, b_o, X, X, 512, 512);
        // x = LN(X) in-place + XB twin -> d_out lower (KQP dead)
        ln1f_kernel<<<Rc / 4, blk, 0, stream>>>(X, n1s + i * 512, n1b + i * 512, XBu);
        // FFN weights -> bf16 twins in d_out UPPER (one dispatch; free until layer end)
        wconv2_kernel<<<(2 * (1048576 / 8) + 255) / 256, blk, 0, stream>>>(
            w_1, W1bD, w_2, W2bD, 1048576 / 8);
        // FFN1: H1 = relu(XB @ W1b^T + b1) bf16 -> B2 full (XPu/AOu dead)
        gemm_bb<1><<<g2048, blk, 0, stream>>>(
            XBu, 512, W1bD, 512, b_1, nullptr, H1u, 2048, 512);
        // FFN2 fused: X = X + H1 @ W2b^T + b2  (K=2048, in-place f32)
        gemm_bb<2><<<g512, blk, 0, stream>>>(
            H1u, 2048, W2bD, 2048, b_2, X, X, 512, 2048);
        // ln2: last layer -> permuted d_out; else fused (X, XP, XB2 for next layer)
        if (i == Lc - 1)
            ln_kernel<true><<<Rc / 4, blk, 0, stream>>>(X, n2s + i * 512, n2b + i * 512, out);
        else
            ln2f_kernel<<<Rc / 4, blk, 0, stream>>>(X, n2s + i * 512, n2b + i * 512,
                                                    pos, XPu, XB2u);
    }
}